// Round 2
// baseline (1180.411 us; speedup 1.0000x reference)
//
#include <hip/hip_runtime.h>
#include <hip/hip_fp16.h>
#include <math.h>

#define U_NUM_ 50000
#define I_NUM_ 50000
#define EMBED_ 64
#define ATT_   64
#define NNZ_   2500000

// ---------------------------------------------------------------------------
// Pass 0: four 50000x64 @ 64x64^T projections, fp32 accumulate, fp16 store.
// E tile + W staged in LDS with coalesced float4 loads. Compute reads:
//   W: stride-65 per-lane -> 2-way bank alias (free)
//   E: wave-uniform float4 -> broadcast (free)
// combo 0: Qu = user @ Wq^T + bq    combo 1: Ki = item @ Wk^T + bk
// combo 2: Qi = item @ Wq^T + bq    combo 3: Ku = user @ Wk^T + bk
// ---------------------------------------------------------------------------
__global__ __launch_bounds__(256) void proj_kernel(
        const float* __restrict__ user_embed, const float* __restrict__ item_embed,
        const float* __restrict__ Wq, const float* __restrict__ bq,
        const float* __restrict__ Wk, const float* __restrict__ bk,
        __half* __restrict__ proj) {
    __shared__ float Wl[ATT_][EMBED_ + 1];
    __shared__ float El[64][EMBED_];
    __shared__ float bl[ATT_];

    const int combo = blockIdx.y;
    const float* E = (combo == 0 || combo == 3) ? user_embed : item_embed;
    const float* W = (combo == 0 || combo == 2) ? Wq : Wk;
    const float* b = (combo == 0 || combo == 2) ? bq : bk;
    __half* out = proj + (size_t)combo * U_NUM_ * ATT_;

    const int tid = threadIdx.x;

    // stage W: 1024 float4 chunks, coalesced; scalar-store into padded LDS
    for (int i4 = tid; i4 < 1024; i4 += 256) {
        const int r = i4 >> 4, c4 = (i4 & 15) * 4;
        float4 w = ((const float4*)W)[i4];
        Wl[r][c4 + 0] = w.x; Wl[r][c4 + 1] = w.y;
        Wl[r][c4 + 2] = w.z; Wl[r][c4 + 3] = w.w;
    }
    if (tid < ATT_) bl[tid] = b[tid];

    // stage E tile: 64 rows x 64 cols, coalesced float4
    const int row0 = blockIdx.x * 64;
    for (int i4 = tid; i4 < 1024; i4 += 256) {
        const int r = i4 >> 4, c4 = (i4 & 15) * 4;
        const int gr = row0 + r;
        float4 ev = make_float4(0.f, 0.f, 0.f, 0.f);
        if (gr < U_NUM_) ev = ((const float4*)(E + (size_t)gr * EMBED_))[i4 & 15];
        *(float4*)&El[r][c4] = ev;
    }
    __syncthreads();

    const int a  = tid & 63;   // output feature
    const int rw = tid >> 6;   // wave id 0..3 -> rows rw, rw+4, ..., rw+60
    float acc[16];
    #pragma unroll
    for (int k = 0; k < 16; ++k) acc[k] = bl[a];

    #pragma unroll
    for (int e4 = 0; e4 < 16; ++e4) {
        const float w0 = Wl[a][e4 * 4 + 0];
        const float w1 = Wl[a][e4 * 4 + 1];
        const float w2 = Wl[a][e4 * 4 + 2];
        const float w3 = Wl[a][e4 * 4 + 3];
        #pragma unroll
        for (int k = 0; k < 16; ++k) {
            float4 ev = *(const float4*)&El[rw + 4 * k][e4 * 4];  // uniform -> broadcast
            acc[k] = fmaf(ev.x, w0, fmaf(ev.y, w1, fmaf(ev.z, w2, fmaf(ev.w, w3, acc[k]))));
        }
    }

    #pragma unroll
    for (int k = 0; k < 16; ++k) {
        const int gr = row0 + rw + 4 * k;
        if (gr < U_NUM_) out[(size_t)gr * ATT_ + a] = __float2half(acc[k]);
    }
}

// ---------------------------------------------------------------------------
// Pass 1: per-edge w = Q[q]·K[k] over fp16 tables; e = exp(w - log(-log(u)));
// atomicAdd into segment sums. 8 lanes per edge: each lane loads 16 B (8
// halves) of Q and K -> one fully-coalesced 128 B line per row; 3-step
// shfl_xor reduce. Max-subtraction skipped (v analytically bounded <= ~31).
// ---------------------------------------------------------------------------
__global__ __launch_bounds__(256) void edge_pass1(
        const int* __restrict__ rows, const int* __restrict__ cols,
        const float* __restrict__ u_ui, const float* __restrict__ u_iu,
        const __half* __restrict__ proj,
        float* __restrict__ out, float* __restrict__ segsum) {
    const __half* Qu = proj + 0 * (size_t)U_NUM_ * ATT_;
    const __half* Ki = proj + 1 * (size_t)U_NUM_ * ATT_;
    const __half* Qi = proj + 2 * (size_t)U_NUM_ * ATT_;
    const __half* Ku = proj + 3 * (size_t)U_NUM_ * ATT_;

    const int lane = threadIdx.x & 7;
    int g = (blockIdx.x * blockDim.x + threadIdx.x) >> 3;
    const int stride = (gridDim.x * blockDim.x) >> 3;

    union H8 { uint4 u; __half2 h[4]; };

    for (; g < 2 * NNZ_; g += stride) {
        int q_idx, k_idx, seg_off;
        const __half *Q, *K;
        float u;
        if (g < NNZ_) {
            q_idx = rows[g]; k_idx = cols[g];
            Q = Qu; K = Ki; u = u_ui[g]; seg_off = 0;
        } else {
            const int j = g - NNZ_;
            q_idx = cols[j]; k_idx = rows[j];
            Q = Qi; K = Ku; u = u_iu[j]; seg_off = U_NUM_;
        }
        H8 qh, kh;
        qh.u = *(const uint4*)(Q + (size_t)q_idx * ATT_ + lane * 8);
        kh.u = *(const uint4*)(K + (size_t)k_idx * ATT_ + lane * 8);
        float p = 0.f;
        #pragma unroll
        for (int j = 0; j < 4; ++j) {
            float2 qf = __half22float2(qh.h[j]);
            float2 kf = __half22float2(kh.h[j]);
            p = fmaf(qf.x, kf.x, p);
            p = fmaf(qf.y, kf.y, p);
        }
        p += __shfl_xor(p, 1);
        p += __shfl_xor(p, 2);
        p += __shfl_xor(p, 4);
        const float gq = logf(-logf(u));
        const float ee = expf(p - gq);       // TAU = 1
        if (lane == 0) {
            out[g] = ee;
            atomicAdd(&segsum[seg_off + q_idx], ee);
        }
    }
}

// ---------------------------------------------------------------------------
// Pass 2: normalize by segment sum, 4 edges per thread (NNZ % 4 == 0 so a
// float4 chunk never straddles the ui/iu boundary).
// ---------------------------------------------------------------------------
__global__ __launch_bounds__(256) void edge_pass2(
        const int* __restrict__ rows, const int* __restrict__ cols,
        const float* __restrict__ segsum, float* __restrict__ out) {
    int i = blockIdx.x * blockDim.x + threadIdx.x;
    const int stride = gridDim.x * blockDim.x;
    const int n4 = (2 * NNZ_) / 4;
    for (; i < n4; i += stride) {
        float4 v = ((const float4*)out)[i];
        const int base = i * 4;
        int4 seg;
        if (base < NNZ_) {
            seg = *(const int4*)(rows + base);
        } else {
            seg = *(const int4*)(cols + (base - NNZ_));
            seg.x += U_NUM_; seg.y += U_NUM_; seg.z += U_NUM_; seg.w += U_NUM_;
        }
        v.x /= segsum[seg.x];
        v.y /= segsum[seg.y];
        v.z /= segsum[seg.z];
        v.w /= segsum[seg.w];
        ((float4*)out)[i] = v;
    }
}

extern "C" void kernel_launch(void* const* d_in, const int* in_sizes, int n_in,
                              void* d_out, int out_size, void* d_ws, size_t ws_size,
                              hipStream_t stream) {
    const float* user_embed = (const float*)d_in[0];
    const float* item_embed = (const float*)d_in[1];
    const float* Wq = (const float*)d_in[2];
    const float* bq = (const float*)d_in[3];
    const float* Wk = (const float*)d_in[4];
    const float* bk = (const float*)d_in[5];
    const int*   rows = (const int*)d_in[6];
    const int*   cols = (const int*)d_in[7];
    const float* u_ui = (const float*)d_in[8];
    const float* u_iu = (const float*)d_in[9];
    float* out = (float*)d_out;

    __half* proj  = (__half*)d_ws;                                 // 4*50000*64 fp16 = 25.6 MB
    float* segsum = (float*)(proj + 4 * (size_t)U_NUM_ * ATT_);    // 100000 f32

    hipMemsetAsync(segsum, 0, (U_NUM_ + I_NUM_) * sizeof(float), stream);

    dim3 pgrid((U_NUM_ + 63) / 64, 4);
    proj_kernel<<<pgrid, 256, 0, stream>>>(user_embed, item_embed, Wq, bq, Wk, bk, proj);

    edge_pass1<<<4096, 256, 0, stream>>>(rows, cols, u_ui, u_iu, proj, out, segsum);
    edge_pass2<<<2048, 256, 0, stream>>>(rows, cols, segsum, out);
}

// Round 3
// 359.128 us; speedup vs baseline: 3.2869x; 3.2869x over previous
//
#include <hip/hip_runtime.h>
#include <hip/hip_fp16.h>
#include <math.h>

#define U_NUM_ 50000
#define I_NUM_ 50000
#define EMBED_ 64
#define ATT_   64
#define NNZ_   2500000

// ---------------------------------------------------------------------------
// Pass 0: four 50000x64 @ 64x64^T projections, fp32 accumulate, fp16 store.
// 32 rows/block, acc[8]/thread (keeps VGPR ~50, no spill — round-1 version
// spilled at acc[16]: VGPR=256, 1.8 GB scratch writes).
// W + E tile staged in LDS via coalesced float4 loads.
//   Wl reads: stride-65 per-lane -> 2-way bank alias (free)
//   El reads: wave-uniform float4 -> broadcast (free)
// combo 0: Qu = user @ Wq^T + bq    combo 1: Ki = item @ Wk^T + bk
// combo 2: Qi = item @ Wq^T + bq    combo 3: Ku = user @ Wk^T + bk
// ---------------------------------------------------------------------------
__global__ __launch_bounds__(256) void proj_kernel(
        const float* __restrict__ user_embed, const float* __restrict__ item_embed,
        const float* __restrict__ Wq, const float* __restrict__ bq,
        const float* __restrict__ Wk, const float* __restrict__ bk,
        __half* __restrict__ proj) {
    __shared__ float Wl[ATT_][EMBED_ + 1];
    __shared__ float El[32][EMBED_];
    __shared__ float bl[ATT_];

    const int combo = blockIdx.y;
    const float* E = (combo == 0 || combo == 3) ? user_embed : item_embed;
    const float* W = (combo == 0 || combo == 2) ? Wq : Wk;
    const float* b = (combo == 0 || combo == 2) ? bq : bk;
    __half* out = proj + (size_t)combo * U_NUM_ * ATT_;

    const int tid = threadIdx.x;

    // stage W: 64x64 f32 = 1024 float4, coalesced; scalar-store into padded LDS
    for (int i4 = tid; i4 < 1024; i4 += 256) {
        const int r = i4 >> 4, c4 = (i4 & 15) * 4;
        float4 w = ((const float4*)W)[i4];
        Wl[r][c4 + 0] = w.x; Wl[r][c4 + 1] = w.y;
        Wl[r][c4 + 2] = w.z; Wl[r][c4 + 3] = w.w;
    }
    if (tid < ATT_) bl[tid] = b[tid];

    // stage E tile: 32 rows x 64 cols = 512 float4, coalesced (2 per thread)
    const int row0 = blockIdx.x * 32;
    for (int i4 = tid; i4 < 512; i4 += 256) {
        const int r = i4 >> 4, c4 = (i4 & 15) * 4;
        const int gr = row0 + r;
        float4 ev = make_float4(0.f, 0.f, 0.f, 0.f);
        if (gr < U_NUM_) ev = ((const float4*)(E + (size_t)gr * EMBED_))[i4 & 15];
        *(float4*)&El[r][c4] = ev;
    }
    __syncthreads();

    const int a  = tid & 63;   // output feature
    const int rw = tid >> 6;   // 0..3: thread handles rows rw+4k, k=0..7
    float acc[8];
    #pragma unroll
    for (int k = 0; k < 8; ++k) acc[k] = bl[a];

    #pragma unroll 2
    for (int e4 = 0; e4 < 16; ++e4) {
        const float w0 = Wl[a][e4 * 4 + 0];
        const float w1 = Wl[a][e4 * 4 + 1];
        const float w2 = Wl[a][e4 * 4 + 2];
        const float w3 = Wl[a][e4 * 4 + 3];
        #pragma unroll
        for (int k = 0; k < 8; ++k) {
            float4 ev = *(const float4*)&El[rw + 4 * k][e4 * 4];  // uniform -> broadcast
            acc[k] = fmaf(ev.x, w0, fmaf(ev.y, w1, fmaf(ev.z, w2, fmaf(ev.w, w3, acc[k]))));
        }
    }

    #pragma unroll
    for (int k = 0; k < 8; ++k) {
        const int gr = row0 + rw + 4 * k;
        if (gr < U_NUM_) out[(size_t)gr * ATT_ + a] = __float2half(acc[k]);
    }
}

// ---------------------------------------------------------------------------
// Pass 1: per-edge w = Q[q]·K[k] over fp16 tables; e = exp(w - log(-log(u)));
// atomicAdd into segment sums. 8 lanes per edge: each lane loads 16 B (8
// halves) of Q and K -> one fully-coalesced 128 B line per row; 3-step
// shfl_xor reduce. Max-subtraction skipped (v analytically bounded <= ~31).
// ---------------------------------------------------------------------------
__global__ __launch_bounds__(256) void edge_pass1(
        const int* __restrict__ rows, const int* __restrict__ cols,
        const float* __restrict__ u_ui, const float* __restrict__ u_iu,
        const __half* __restrict__ proj,
        float* __restrict__ out, float* __restrict__ segsum) {
    const __half* Qu = proj + 0 * (size_t)U_NUM_ * ATT_;
    const __half* Ki = proj + 1 * (size_t)U_NUM_ * ATT_;
    const __half* Qi = proj + 2 * (size_t)U_NUM_ * ATT_;
    const __half* Ku = proj + 3 * (size_t)U_NUM_ * ATT_;

    const int lane = threadIdx.x & 7;
    int g = (blockIdx.x * blockDim.x + threadIdx.x) >> 3;
    const int stride = (gridDim.x * blockDim.x) >> 3;

    union H8 { uint4 u; __half2 h[4]; };

    for (; g < 2 * NNZ_; g += stride) {
        int q_idx, k_idx, seg_off;
        const __half *Q, *K;
        float u;
        if (g < NNZ_) {
            q_idx = rows[g]; k_idx = cols[g];
            Q = Qu; K = Ki; u = u_ui[g]; seg_off = 0;
        } else {
            const int j = g - NNZ_;
            q_idx = cols[j]; k_idx = rows[j];
            Q = Qi; K = Ku; u = u_iu[j]; seg_off = U_NUM_;
        }
        H8 qh, kh;
        qh.u = *(const uint4*)(Q + (size_t)q_idx * ATT_ + lane * 8);
        kh.u = *(const uint4*)(K + (size_t)k_idx * ATT_ + lane * 8);
        float p = 0.f;
        #pragma unroll
        for (int j = 0; j < 4; ++j) {
            float2 qf = __half22float2(qh.h[j]);
            float2 kf = __half22float2(kh.h[j]);
            p = fmaf(qf.x, kf.x, p);
            p = fmaf(qf.y, kf.y, p);
        }
        p += __shfl_xor(p, 1);
        p += __shfl_xor(p, 2);
        p += __shfl_xor(p, 4);
        const float gq = logf(-logf(u));
        const float ee = expf(p - gq);       // TAU = 1
        if (lane == 0) {
            out[g] = ee;
            atomicAdd(&segsum[seg_off + q_idx], ee);
        }
    }
}

// ---------------------------------------------------------------------------
// Pass 2: normalize by segment sum, 4 edges per thread (NNZ % 4 == 0 so a
// float4 chunk never straddles the ui/iu boundary).
// ---------------------------------------------------------------------------
__global__ __launch_bounds__(256) void edge_pass2(
        const int* __restrict__ rows, const int* __restrict__ cols,
        const float* __restrict__ segsum, float* __restrict__ out) {
    int i = blockIdx.x * blockDim.x + threadIdx.x;
    const int stride = gridDim.x * blockDim.x;
    const int n4 = (2 * NNZ_) / 4;
    for (; i < n4; i += stride) {
        float4 v = ((const float4*)out)[i];
        const int base = i * 4;
        int4 seg;
        if (base < NNZ_) {
            seg = *(const int4*)(rows + base);
        } else {
            seg = *(const int4*)(cols + (base - NNZ_));
            seg.x += U_NUM_; seg.y += U_NUM_; seg.z += U_NUM_; seg.w += U_NUM_;
        }
        v.x /= segsum[seg.x];
        v.y /= segsum[seg.y];
        v.z /= segsum[seg.z];
        v.w /= segsum[seg.w];
        ((float4*)out)[i] = v;
    }
}

extern "C" void kernel_launch(void* const* d_in, const int* in_sizes, int n_in,
                              void* d_out, int out_size, void* d_ws, size_t ws_size,
                              hipStream_t stream) {
    const float* user_embed = (const float*)d_in[0];
    const float* item_embed = (const float*)d_in[1];
    const float* Wq = (const float*)d_in[2];
    const float* bq = (const float*)d_in[3];
    const float* Wk = (const float*)d_in[4];
    const float* bk = (const float*)d_in[5];
    const int*   rows = (const int*)d_in[6];
    const int*   cols = (const int*)d_in[7];
    const float* u_ui = (const float*)d_in[8];
    const float* u_iu = (const float*)d_in[9];
    float* out = (float*)d_out;

    __half* proj  = (__half*)d_ws;                                 // 4*50000*64 fp16 = 25.6 MB
    float* segsum = (float*)(proj + 4 * (size_t)U_NUM_ * ATT_);    // 100000 f32

    hipMemsetAsync(segsum, 0, (U_NUM_ + I_NUM_) * sizeof(float), stream);

    dim3 pgrid((U_NUM_ + 31) / 32, 4);
    proj_kernel<<<pgrid, 256, 0, stream>>>(user_embed, item_embed, Wq, bq, Wk, bk, proj);

    edge_pass1<<<4096, 256, 0, stream>>>(rows, cols, u_ui, u_iu, proj, out, segsum);
    edge_pass2<<<2048, 256, 0, stream>>>(rows, cols, segsum, out);
}

// Round 4
// 340.525 us; speedup vs baseline: 3.4664x; 1.0546x over previous
//
#include <hip/hip_runtime.h>
#include <hip/hip_fp16.h>
#include <math.h>

#define U_NUM_ 50000
#define I_NUM_ 50000
#define EMBED_ 64
#define ATT_   64
#define NNZ_   2500000

// ---------------------------------------------------------------------------
// Pass 0: four 50000x64 @ 64x64^T projections, fp32 accumulate, fp16 store,
// written INTERLEAVED so one edge gather serves both the ui and iu halves:
//   utab[row][  0: 64] = Qu = user @ Wq^T + bq   (combo 0)
//   utab[row][ 64:128] = Ku = user @ Wk^T + bk   (combo 3)
//   itab[col][  0: 64] = Ki = item @ Wk^T + bk   (combo 1)
//   itab[col][ 64:128] = Qi = item @ Wq^T + bq   (combo 2)
// 32 rows/block, acc[8]/thread (VGPR-safe; round-1's acc[16] spilled).
// ---------------------------------------------------------------------------
__global__ __launch_bounds__(256) void proj_kernel(
        const float* __restrict__ user_embed, const float* __restrict__ item_embed,
        const float* __restrict__ Wq, const float* __restrict__ bq,
        const float* __restrict__ Wk, const float* __restrict__ bk,
        __half* __restrict__ utab, __half* __restrict__ itab) {
    __shared__ float Wl[ATT_][EMBED_ + 1];
    __shared__ float El[32][EMBED_];
    __shared__ float bl[ATT_];

    const int combo = blockIdx.y;
    const float* E = (combo == 0 || combo == 3) ? user_embed : item_embed;
    const float* W = (combo == 0 || combo == 2) ? Wq : Wk;
    const float* b = (combo == 0 || combo == 2) ? bq : bk;
    __half* tab    = (combo == 0 || combo == 3) ? utab : itab;
    const int off  = (combo == 0 || combo == 1) ? 0 : 64;

    const int tid = threadIdx.x;

    for (int i4 = tid; i4 < 1024; i4 += 256) {
        const int r = i4 >> 4, c4 = (i4 & 15) * 4;
        float4 w = ((const float4*)W)[i4];
        Wl[r][c4 + 0] = w.x; Wl[r][c4 + 1] = w.y;
        Wl[r][c4 + 2] = w.z; Wl[r][c4 + 3] = w.w;
    }
    if (tid < ATT_) bl[tid] = b[tid];

    const int row0 = blockIdx.x * 32;
    for (int i4 = tid; i4 < 512; i4 += 256) {
        const int r = i4 >> 4, c4 = (i4 & 15) * 4;
        const int gr = row0 + r;
        float4 ev = make_float4(0.f, 0.f, 0.f, 0.f);
        if (gr < U_NUM_) ev = ((const float4*)(E + (size_t)gr * EMBED_))[i4 & 15];
        *(float4*)&El[r][c4] = ev;
    }
    __syncthreads();

    const int a  = tid & 63;
    const int rw = tid >> 6;
    float acc[8];
    #pragma unroll
    for (int k = 0; k < 8; ++k) acc[k] = bl[a];

    #pragma unroll 2
    for (int e4 = 0; e4 < 16; ++e4) {
        const float w0 = Wl[a][e4 * 4 + 0];
        const float w1 = Wl[a][e4 * 4 + 1];
        const float w2 = Wl[a][e4 * 4 + 2];
        const float w3 = Wl[a][e4 * 4 + 3];
        #pragma unroll
        for (int k = 0; k < 8; ++k) {
            float4 ev = *(const float4*)&El[rw + 4 * k][e4 * 4];
            acc[k] = fmaf(ev.x, w0, fmaf(ev.y, w1, fmaf(ev.z, w2, fmaf(ev.w, w3, acc[k]))));
        }
    }

    #pragma unroll
    for (int k = 0; k < 8; ++k) {
        const int gr = row0 + rw + 4 * k;
        if (gr < U_NUM_) tab[(size_t)gr * 128 + off + a] = __float2half(acc[k]);
    }
}

// ---------------------------------------------------------------------------
// Pass 1: fused ui+iu edge pass. 16 lanes per COO entry j; lane l loads 16 B
// chunk l of utab[rows[j]] (256 B) and itab[cols[j]] (256 B). The per-lane
// partial dot gives: lanes 0-7 -> Qu·Ki (ui edge), lanes 8-15 -> Ku·Qi (iu
// edge); a 3-step shfl_xor tree reduces both halves at once. 2x unrolled
// (edges j and j+NNZ/2) for 4 in-flight gathers per lane.
// Max-subtraction skipped: v analytically bounded (<= ~31), exp fits f32.
// ---------------------------------------------------------------------------
__global__ __launch_bounds__(256) void edge_pass1(
        const int* __restrict__ rows, const int* __restrict__ cols,
        const float* __restrict__ u_ui, const float* __restrict__ u_iu,
        const __half* __restrict__ utab, const __half* __restrict__ itab,
        float* __restrict__ out, float* __restrict__ segsum) {
    const int lane = threadIdx.x & 15;
    const int g = (blockIdx.x * blockDim.x + threadIdx.x) >> 4;
    if (g >= NNZ_ / 2) return;
    const int j0 = g;
    const int j1 = g + NNZ_ / 2;

    const int r0 = rows[j0], c0 = cols[j0];
    const int r1 = rows[j1], c1 = cols[j1];

    const uint4* up = (const uint4*)utab;   // 16 chunks of 16 B per row
    const uint4* ip = (const uint4*)itab;

    union H8 { uint4 u; __half2 h[4]; };
    H8 uv0, iv0, uv1, iv1;
    uv0.u = up[(size_t)r0 * 16 + lane];
    iv0.u = ip[(size_t)c0 * 16 + lane];
    uv1.u = up[(size_t)r1 * 16 + lane];
    iv1.u = ip[(size_t)c1 * 16 + lane];

    float p0 = 0.f, p1 = 0.f;
    #pragma unroll
    for (int m = 0; m < 4; ++m) {
        float2 a0 = __half22float2(uv0.h[m]), b0 = __half22float2(iv0.h[m]);
        float2 a1 = __half22float2(uv1.h[m]), b1 = __half22float2(iv1.h[m]);
        p0 = fmaf(a0.x, b0.x, p0); p0 = fmaf(a0.y, b0.y, p0);
        p1 = fmaf(a1.x, b1.x, p1); p1 = fmaf(a1.y, b1.y, p1);
    }
    p0 += __shfl_xor(p0, 1); p1 += __shfl_xor(p1, 1);
    p0 += __shfl_xor(p0, 2); p1 += __shfl_xor(p1, 2);
    p0 += __shfl_xor(p0, 4); p1 += __shfl_xor(p1, 4);
    // lanes 0-7: w_ui; lanes 8-15: w_iu (for both edges)

    const bool iu = (lane & 8) != 0;
    const float un0 = iu ? u_iu[j0] : u_ui[j0];
    const float un1 = iu ? u_iu[j1] : u_ui[j1];
    const float e0 = expf(p0 - logf(-logf(un0)));   // TAU = 1
    const float e1 = expf(p1 - logf(-logf(un1)));

    if (lane == 0) {
        out[j0] = e0; atomicAdd(&segsum[r0], e0);
        out[j1] = e1; atomicAdd(&segsum[r1], e1);
    } else if (lane == 8) {
        out[NNZ_ + j0] = e0; atomicAdd(&segsum[U_NUM_ + c0], e0);
        out[NNZ_ + j1] = e1; atomicAdd(&segsum[U_NUM_ + c1], e1);
    }
}

// ---------------------------------------------------------------------------
// Pass 2: normalize by segment sum, 4 edges per thread.
// ---------------------------------------------------------------------------
__global__ __launch_bounds__(256) void edge_pass2(
        const int* __restrict__ rows, const int* __restrict__ cols,
        const float* __restrict__ segsum, float* __restrict__ out) {
    int i = blockIdx.x * blockDim.x + threadIdx.x;
    const int stride = gridDim.x * blockDim.x;
    const int n4 = (2 * NNZ_) / 4;
    for (; i < n4; i += stride) {
        float4 v = ((const float4*)out)[i];
        const int base = i * 4;
        int4 seg;
        if (base < NNZ_) {
            seg = *(const int4*)(rows + base);
        } else {
            seg = *(const int4*)(cols + (base - NNZ_));
            seg.x += U_NUM_; seg.y += U_NUM_; seg.z += U_NUM_; seg.w += U_NUM_;
        }
        v.x /= segsum[seg.x];
        v.y /= segsum[seg.y];
        v.z /= segsum[seg.z];
        v.w /= segsum[seg.w];
        ((float4*)out)[i] = v;
    }
}

extern "C" void kernel_launch(void* const* d_in, const int* in_sizes, int n_in,
                              void* d_out, int out_size, void* d_ws, size_t ws_size,
                              hipStream_t stream) {
    const float* user_embed = (const float*)d_in[0];
    const float* item_embed = (const float*)d_in[1];
    const float* Wq = (const float*)d_in[2];
    const float* bq = (const float*)d_in[3];
    const float* Wk = (const float*)d_in[4];
    const float* bk = (const float*)d_in[5];
    const int*   rows = (const int*)d_in[6];
    const int*   cols = (const int*)d_in[7];
    const float* u_ui = (const float*)d_in[8];
    const float* u_iu = (const float*)d_in[9];
    float* out = (float*)d_out;

    __half* utab  = (__half*)d_ws;                                 // 50000*128 fp16 = 12.8 MB
    __half* itab  = utab + (size_t)U_NUM_ * 128;                   // 12.8 MB
    float* segsum = (float*)(itab + (size_t)I_NUM_ * 128);         // 100000 f32

    hipMemsetAsync(segsum, 0, (U_NUM_ + I_NUM_) * sizeof(float), stream);

    dim3 pgrid((U_NUM_ + 31) / 32, 4);
    proj_kernel<<<pgrid, 256, 0, stream>>>(user_embed, item_embed, Wq, bq, Wk, bk, utab, itab);

    // NNZ/2 groups of 16 lanes, one iteration each
    const int groups = NNZ_ / 2;
    edge_pass1<<<(groups * 16) / 256, 256, 0, stream>>>(rows, cols, u_ui, u_iu, utab, itab, out, segsum);
    edge_pass2<<<2048, 256, 0, stream>>>(rows, cols, segsum, out);
}